// Round 8
// baseline (345.252 us; speedup 1.0000x reference)
//
#include <hip/hip_runtime.h>
#include <hip/hip_fp16.h>

#define BB 4
#define CC 3
#define HH 384
#define WW 384
#define FF 5
#define KK 25            // FF*FF
#define HW (HH*WW)

#define TX 64            // tile width (pixels): 32 threads-x * 2 px
#define TY 8             // tile height
#define MX 12            // x stage margin (left); right margin = 12
#define MY 10            // y stage margin (top); bottom = 10
#define SX (TX+2*MX)     // 88 staged pixels per row
#define SY (TY+2*MY)     // 28 staged rows

typedef float fx2 __attribute__((ext_vector_type(2)));

__device__ __forceinline__ fx2 nt_load2(const float* p) {
    return __builtin_nontemporal_load((const fx2*)p);
}

// pack one pixel (3 fp32 ch) -> 8B: .x = h(c0)|h(c1)<<16, .y = h(c2)
__device__ __forceinline__ uint2 pack_px(float c0, float c1, float c2) {
    __half2 h01 = __floats2half2_rn(c0, c1);
    uint2 r;
    r.x = *(const unsigned int*)&h01;
    r.y = (unsigned int)__half_as_ushort(__float2half_rn(c2));
    return r;
}

__device__ __forceinline__ void unpack_px(uint2 q, float& c0, float& c1, float& c2) {
    float2 f01 = __half22float2(*(const __half2*)&q.x);
    c0 = f01.x; c1 = f01.y;
    c2 = __half2float(*(const __half*)&q.y);
}

// Pre-pass: (B,C,H,W) planar fp32 -> (B,H*W) fp16 channel-packed uint2 (8B/px)
__global__ __launch_bounds__(256) void pack_kernel(
    const float* __restrict__ inp, uint2* __restrict__ tab)
{
    int t = blockIdx.x * blockDim.x + threadIdx.x;
    if (t >= BB * HW) return;
    int b = t / HW;
    int i = t - b * HW;
    const float* base = inp + (size_t)b * CC * HW + i;
    tab[t] = pack_px(base[0], base[HW], base[2 * HW]);
}

// Block = 64x8 output tile, 256 threads (2 px/thread).
// Stage 88x28 fp16 window in LDS; all bilinear gathers hit LDS (global
// fallback only if an offset exceeds the 10-12px margin — never in practice,
// but kept for correctness).
__global__ __launch_bounds__(256, 4) void dsepconv_kernel(
    const uint2* __restrict__ tab,
    const float* __restrict__ vert,
    const float* __restrict__ horiz,
    const float* __restrict__ offx,
    const float* __restrict__ offy,
    const float* __restrict__ mask,
    float* __restrict__ out)
{
    __shared__ uint2 sm[SY][SX];   // 28*88*8 = 19712 B

    int b  = blockIdx.z;
    int X0 = blockIdx.x * TX;
    int Y0 = blockIdx.y * TY;
    int XS0 = X0 - MX;
    int YS0 = Y0 - MY;

    const uint2* tb = tab + (size_t)b * HW;

    // ---- stage: 28 rows x 44 pixel-pairs ----
    for (int c = threadIdx.x; c < SY * (SX / 2); c += 256) {
        int sy  = c / (SX / 2);
        int sxp = c - sy * (SX / 2);
        int gy  = min(max(YS0 + sy, 0), HH - 1);
        int gx0 = min(max(XS0 + 2 * sxp,     0), WW - 1);
        int gx1 = min(max(XS0 + 2 * sxp + 1, 0), WW - 1);
        sm[sy][2 * sxp]     = tb[gy * WW + gx0];
        sm[sy][2 * sxp + 1] = tb[gy * WW + gx1];
    }
    __syncthreads();

    int tx = threadIdx.x & 31;
    int ty = threadIdx.x >> 5;
    int xb = X0 + tx * 2;
    int y  = Y0 + ty;
    int planeoff = y * WW + xb;

    fx2 v2[FF], h2[FF];
#pragma unroll
    for (int f = 0; f < FF; ++f) {
        v2[f] = nt_load2(vert  + (b * FF + f) * HW + planeoff);
        h2[f] = nt_load2(horiz + (b * FF + f) * HW + planeoff);
    }

    float acc[2][3] = {{0.f,0.f,0.f},{0.f,0.f,0.f}};
    const float fy = (float)y;

    for (int ki = 0; ki < FF; ++ki) {
        float dy = fy + (float)(ki - 2);
        const float* ox_p = offx + (size_t)(b * KK + ki * FF) * HW + planeoff;
        const float* oy_p = offy + (size_t)(b * KK + ki * FF) * HW + planeoff;
        const float* m_p  = mask + (size_t)(b * KK + ki * FF) * HW + planeoff;
#pragma unroll
        for (int kj = 0; kj < FF; ++kj) {
            fx2 ox2 = nt_load2(ox_p + kj * HW);
            fx2 oy2 = nt_load2(oy_p + kj * HW);
            fx2 m2  = nt_load2(m_p  + kj * HW);
#pragma unroll
            for (int p = 0; p < 2; ++p) {
                float wt = v2[ki][p] * h2[kj][p] * m2[p];
                float py = oy2[p] + dy;
                float px = ox2[p] + (float)(xb + p + kj - 2);
                py = fminf(fmaxf(py, 0.f), (float)(HH - 1));
                px = fminf(fmaxf(px, 0.f), (float)(WW - 1));
                float y0f = floorf(py);
                float x0f = floorf(px);
                float wy = py - y0f;
                float wx = px - x0f;
                int y0 = (int)y0f;
                int x0 = (int)x0f;
                int y1 = min(y0 + 1, HH - 1);
                int x1 = min(x0 + 1, WW - 1);

                int sy0 = y0 - YS0, sy1 = y1 - YS0;
                int sx0 = x0 - XS0, sx1 = x1 - XS0;

                uint2 q00, q01, q10, q11;
                if (sy0 >= 0 && sy1 < SY && sx0 >= 0 && sx1 < SX) {
                    q00 = sm[sy0][sx0];
                    q01 = sm[sy0][sx1];
                    q10 = sm[sy1][sx0];
                    q11 = sm[sy1][sx1];
                } else {   // out-of-window fallback (never in practice)
                    q00 = tb[y0 * WW + x0];
                    q01 = tb[y0 * WW + x1];
                    q10 = tb[y1 * WW + x0];
                    q11 = tb[y1 * WW + x1];
                }

                float a0,a1,a2, b0,b1,b2, c0,c1,c2, d0,d1,d2;
                unpack_px(q00, a0,a1,a2);
                unpack_px(q01, b0,b1,b2);
                unpack_px(q10, c0,c1,c2);
                unpack_px(q11, d0,d1,d2);

                float w00 = (1.f - wy) * (1.f - wx);
                float w01 = (1.f - wy) * wx;
                float w10 = wy * (1.f - wx);
                float w11 = wy * wx;

                acc[p][0] += wt * (a0*w00 + b0*w01 + c0*w10 + d0*w11);
                acc[p][1] += wt * (a1*w00 + b1*w01 + c1*w10 + d1*w11);
                acc[p][2] += wt * (a2*w00 + b2*w01 + c2*w10 + d2*w11);
            }
        }
    }

#pragma unroll
    for (int c = 0; c < CC; ++c) {
        fx2 o; o.x = acc[0][c]; o.y = acc[1][c];
        *(fx2*)(out + ((size_t)b * CC + c) * HW + planeoff) = o;
    }
}

extern "C" void kernel_launch(void* const* d_in, const int* in_sizes, int n_in,
                              void* d_out, int out_size, void* d_ws, size_t ws_size,
                              hipStream_t stream) {
    const float* inp   = (const float*)d_in[0];
    const float* vert  = (const float*)d_in[1];
    const float* horiz = (const float*)d_in[2];
    const float* offx  = (const float*)d_in[3];
    const float* offy  = (const float*)d_in[4];
    const float* mask  = (const float*)d_in[5];
    float* out = (float*)d_out;
    uint2* tab = (uint2*)d_ws;   // 4.72 MB

    {
        int total = BB * HW;
        pack_kernel<<<(total + 255) / 256, 256, 0, stream>>>(inp, tab);
    }
    {
        dim3 grid(WW / TX, HH / TY, BB);   // 6 x 48 x 4
        dsepconv_kernel<<<grid, 256, 0, stream>>>(
            tab, vert, horiz, offx, offy, mask, out);
    }
}